// Round 1
// baseline (1055.398 us; speedup 1.0000x reference)
//
#include <hip/hip_runtime.h>
#include <cstddef>

#define TPB 256

__device__ __forceinline__ float sigmoidf_(float x) {
  return 1.0f / (1.0f + __expf(-x));
}

// jax.image.resize bilinear 21->42, half-pixel centers, edge-renormalized
__device__ __forceinline__ void rzmap(int i, int& j0, int& j1, float& w0, float& w1) {
  if (i == 0)            { j0 = 0;  j1 = 0;  w0 = 1.0f;  w1 = 0.0f; }
  else if (i == 41)      { j0 = 20; j1 = 20; w0 = 1.0f;  w1 = 0.0f; }
  else if ((i & 1) == 0) { int k = i >> 1; j0 = k - 1; j1 = k;     w0 = 0.25f; w1 = 0.75f; }
  else                   { int k = i >> 1; j0 = k;     j1 = k + 1; w0 = 0.75f; w1 = 0.25f; }
}

// K1: per (b, group of 32 ch): gates (means -> dwconv -> GN -> sigmoid) and
// gated projection onto mb1_w accumulated atomically into plc[b][16][441].
__global__ __launch_bounds__(256) void k1_gate_proj(
    const float* __restrict__ FL, const float* __restrict__ scw,
    const float* __restrict__ gng, const float* __restrict__ gnb,
    const float* __restrict__ mb1w, float* __restrict__ plc) {
  const int g = blockIdx.x, b = blockIdx.y;
  const int tid = threadIdx.x;
  __shared__ __align__(16) float slab[32 * 441];
  __shared__ float rm[672], cm[672], ch[672], cw[672];
  __shared__ float red[16];

  const float* base = FL + ((size_t)b * 512 + g * 32) * 441;
  const float4* b4 = (const float4*)base;
  float4* sl4 = (float4*)slab;
  for (int i = tid; i < 3528; i += TPB) sl4[i] = b4[i];
  __syncthreads();

  // row means (over w) and col means (over h): 32ch x 21
  for (int idx = tid; idx < 672; idx += TPB) {
    int c = idx / 21, l = idx - c * 21;
    const float* rowp = slab + c * 441 + l * 21;
    float sr = 0.0f;
    #pragma unroll
    for (int w = 0; w < 21; ++w) sr += rowp[w];
    rm[idx] = sr * (1.0f / 21.0f);
    const float* colp = slab + c * 441 + l;
    float sc = 0.0f;
    #pragma unroll
    for (int h = 0; h < 21; ++h) sc += colp[h * 21];
    cm[idx] = sc * (1.0f / 21.0f);
  }
  __syncthreads();

  // depthwise conv1d, k=7, pad 3 (cross-correlation, zero pad)
  for (int idx = tid; idx < 672; idx += TPB) {
    int c = idx / 21, l = idx - c * 21;
    const float* w7 = scw + (g * 32 + c) * 7;
    float ah = 0.0f, aw = 0.0f;
    #pragma unroll
    for (int t = 0; t < 7; ++t) {
      int ll = l + t - 3;
      if (ll >= 0 && ll < 21) {
        float wt = w7[t];
        ah += rm[c * 21 + ll] * wt;
        aw += cm[c * 21 + ll] * wt;
      }
    }
    ch[idx] = ah; cw[idx] = aw;
  }
  __syncthreads();

  // group-norm stats over the 672 values of each gate
  float s1 = 0.0f, s2 = 0.0f, s3 = 0.0f, s4v = 0.0f;
  for (int idx = tid; idx < 672; idx += TPB) {
    float x = ch[idx], y = cw[idx];
    s1 += x; s2 += x * x; s3 += y; s4v += y * y;
  }
  #pragma unroll
  for (int off = 32; off; off >>= 1) {
    s1 += __shfl_down(s1, off); s2 += __shfl_down(s2, off);
    s3 += __shfl_down(s3, off); s4v += __shfl_down(s4v, off);
  }
  if ((tid & 63) == 0) {
    int wv = tid >> 6;
    red[wv * 4 + 0] = s1; red[wv * 4 + 1] = s2;
    red[wv * 4 + 2] = s3; red[wv * 4 + 3] = s4v;
  }
  __syncthreads();
  const float S1 = red[0] + red[4] + red[8] + red[12];
  const float S2 = red[1] + red[5] + red[9] + red[13];
  const float S3 = red[2] + red[6] + red[10] + red[14];
  const float S4 = red[3] + red[7] + red[11] + red[15];
  const float invn = 1.0f / 672.0f;
  const float mh = S1 * invn, vh = S2 * invn - mh * mh;
  const float mw = S3 * invn, vw = S4 * invn - mw * mw;
  const float ivh = rsqrtf(vh + 1e-5f), ivw = rsqrtf(vw + 1e-5f);

  for (int idx = tid; idx < 672; idx += TPB) {
    int c = idx / 21;
    float gamma = gng[g * 32 + c], beta = gnb[g * 32 + c];
    ch[idx] = sigmoidf_((ch[idx] - mh) * ivh * gamma + beta);
    cw[idx] = sigmoidf_((cw[idx] - mw) * ivw * gamma + beta);
  }
  __syncthreads();

  // gated projection: plc[b][o][p] += sum_c mb1w[o][C] * FL*gh*gw
  float* pp = plc + (size_t)b * 16 * 441;
  for (int p = tid; p < 441; p += TPB) {
    int i = p / 21, j = p - i * 21;
    float acc[16];
    #pragma unroll
    for (int o = 0; o < 16; ++o) acc[o] = 0.0f;
    #pragma unroll 4
    for (int c = 0; c < 32; ++c) {
      float v = slab[c * 441 + p] * ch[c * 21 + i] * cw[c * 21 + j];
      const float* wc = mb1w + g * 32 + c;  // uniform addresses -> s_load
      #pragma unroll
      for (int o = 0; o < 16; ++o) acc[o] += v * wc[o * 512];
    }
    #pragma unroll
    for (int o = 0; o < 16; ++o) atomicAdd(pp + (size_t)o * 441 + p, acc[o]);
  }
}

// K2: bilinear resize of 16-ch plc -> bn -> relu -> mb2 -> sigmoid mask; sow sums
__global__ __launch_bounds__(256) void k2_mask(
    const float* __restrict__ plc, const float* __restrict__ mb1b,
    const float* __restrict__ bng, const float* __restrict__ bnb,
    const float* __restrict__ mb2w, const float* __restrict__ mb2b,
    float* __restrict__ mask, float* __restrict__ sow) {
  const int b = blockIdx.x;
  const int p = blockIdx.y * TPB + threadIdx.x;
  float macc[5] = {0, 0, 0, 0, 0};
  if (p < 1764) {
    int y = p / 42, x = p - y * 42;
    int jy0, jy1, jx0, jx1; float wy0, wy1, wx0, wx1;
    rzmap(y, jy0, jy1, wy0, wy1);
    rzmap(x, jx0, jx1, wx0, wx1);
    const float RSQ = rsqrtf(1.0f + 1e-5f);
    const float* pb = plc + (size_t)b * 16 * 441;
    float h[16];
    #pragma unroll
    for (int o = 0; o < 16; ++o) {
      const float* po = pb + o * 441;
      float hm = wy0 * (wx0 * po[jy0 * 21 + jx0] + wx1 * po[jy0 * 21 + jx1]) +
                 wy1 * (wx0 * po[jy1 * 21 + jx0] + wx1 * po[jy1 * 21 + jx1]);
      float t = (hm + mb1b[o]) * (bng[o] * RSQ) + bnb[o];
      h[o] = t > 0.0f ? t : 0.0f;
    }
    #pragma unroll
    for (int d = 0; d < 5; ++d) {
      float acc = mb2b[d];
      #pragma unroll
      for (int o = 0; o < 16; ++o) acc += mb2w[d * 16 + o] * h[o];
      float mv = sigmoidf_(acc);
      mask[((size_t)b * 5 + d) * 1764 + p] = mv;
      macc[d] = mv;
    }
  }
  #pragma unroll
  for (int off = 32; off; off >>= 1) {
    #pragma unroll
    for (int d = 0; d < 5; ++d) macc[d] += __shfl_down(macc[d], off);
  }
  if ((threadIdx.x & 63) == 0) {
    #pragma unroll
    for (int d = 0; d < 5; ++d) atomicAdd(&sow[b * 5 + d], macc[d]);
  }
}

// K3: vec[b,c,d] = (sum_p F1[b,c,p]*mask[b,d,p]) / (sow+1e-5); writes raw and
// bn1d-scaled transposed-free row-major copies. Streams F1 at HBM BW.
__global__ __launch_bounds__(256) void k3_vec(
    const float* __restrict__ F1, const float* __restrict__ mask,
    const float* __restrict__ sow, const float* __restrict__ g1d,
    float* __restrict__ vec_s, float* __restrict__ vec_r) {
  const int ct = blockIdx.x, b = blockIdx.y;
  __shared__ float4 mkv[2205];
  const float4* msrc = (const float4*)(mask + (size_t)b * 8820);
  for (int i = threadIdx.x; i < 2205; i += TPB) mkv[i] = msrc[i];
  __syncthreads();
  const int wv = threadIdx.x >> 6, lane = threadIdx.x & 63;
  const float RSQ = rsqrtf(1.0f + 1e-5f);
  for (int cc = wv; cc < 16; cc += 4) {
    const int c = ct * 16 + cc;
    const float4* f1v = (const float4*)(F1 + ((size_t)b * 640 + c) * 1764);
    float a[5] = {0, 0, 0, 0, 0};
    for (int q = lane; q < 441; q += 64) {
      float4 f = f1v[q];
      #pragma unroll
      for (int d = 0; d < 5; ++d) {
        float4 m = mkv[d * 441 + q];
        a[d] += f.x * m.x + f.y * m.y + f.z * m.z + f.w * m.w;
      }
    }
    #pragma unroll
    for (int off = 32; off; off >>= 1) {
      #pragma unroll
      for (int d = 0; d < 5; ++d) a[d] += __shfl_down(a[d], off);
    }
    if (lane == 0) {
      #pragma unroll
      for (int d = 0; d < 5; ++d) {
        float inv = 1.0f / (sow[b * 5 + d] + 1e-5f);
        float val = a[d] * inv;
        int k = c * 5 + d;
        vec_r[(size_t)b * 3200 + k] = val;
        vec_s[(size_t)b * 3200 + k] = val * (g1d[k] * RSQ);
      }
    }
  }
}

// K4: z = elu(vec_s @ lin_w^T + c0 + lin_b); out = 0.5 z + 0.5 vec_r.
// thread = m row (m==127 is the virtual bn1d_b row producing the per-n
// constant c0). n indices are blockIdx-derived -> lin_w loads are scalar.
__global__ __launch_bounds__(128) void k4_gemm(
    const float* __restrict__ vec_s, const float* __restrict__ vec_r,
    const float* __restrict__ linw, const float* __restrict__ linb,
    const float* __restrict__ b1d, float* __restrict__ sup,
    float* __restrict__ outq) {
  const int n0 = blockIdx.x * 8;
  const int m = threadIdx.x;
  __shared__ float c0sh[8];
  const float* vrow = (m == 127) ? b1d : (vec_s + (size_t)(m < 100 ? m : 0) * 3200);
  const float* w0 = linw + (size_t)n0 * 3200;
  float acc[8];
  #pragma unroll
  for (int j = 0; j < 8; ++j) acc[j] = 0.0f;
  for (int k = 0; k < 3200; k += 4) {
    float4 v = *(const float4*)(vrow + k);
    #pragma unroll
    for (int j = 0; j < 8; ++j) {
      float4 w = *(const float4*)(w0 + (size_t)j * 3200 + k);
      acc[j] += v.x * w.x + v.y * w.y + v.z * w.z + v.w * w.w;
    }
  }
  if (m == 127) {
    #pragma unroll
    for (int j = 0; j < 8; ++j) c0sh[j] = acc[j];
  }
  __syncthreads();
  if (m < 100) {
    #pragma unroll
    for (int j = 0; j < 8; ++j) {
      int n = n0 + j;
      float dv = acc[j] + c0sh[j] + linb[n];
      float z = dv > 0.0f ? dv : expm1f(dv);
      float o = 0.5f * z + 0.5f * vec_r[(size_t)m * 3200 + n];
      if (m >= 25) outq[(size_t)(m - 20) * 3200 + n] = o;  // query rows 5..79
      else sup[(size_t)m * 3200 + n] = o;
    }
  }
}

// K5: support = mean over 5 shots of first 25 rows
__global__ __launch_bounds__(256) void k5_support(
    const float* __restrict__ sup, float* __restrict__ outp) {
  int idx = blockIdx.x * TPB + threadIdx.x;
  if (idx >= 16000) return;
  int w = idx / 3200, n = idx - w * 3200;
  float s = 0.0f;
  #pragma unroll
  for (int t = 0; t < 5; ++t) s += sup[(size_t)(w * 5 + t) * 3200 + n];
  outp[idx] = s * 0.2f;
}

extern "C" void kernel_launch(void* const* d_in, const int* in_sizes, int n_in,
                              void* d_out, int out_size, void* d_ws, size_t ws_size,
                              hipStream_t stream) {
  const float* F1   = (const float*)d_in[0];
  const float* FL   = (const float*)d_in[1];
  const float* scw  = (const float*)d_in[2];
  const float* gng  = (const float*)d_in[3];
  const float* gnb  = (const float*)d_in[4];
  const float* mb1w = (const float*)d_in[5];
  const float* mb1b = (const float*)d_in[6];
  const float* bng  = (const float*)d_in[7];
  const float* bnb  = (const float*)d_in[8];
  const float* mb2w = (const float*)d_in[9];
  const float* mb2b = (const float*)d_in[10];
  const float* g1d  = (const float*)d_in[11];
  const float* b1d  = (const float*)d_in[12];
  const float* linw = (const float*)d_in[13];
  const float* linb = (const float*)d_in[14];
  // way/shot fixed at 5/5 per problem constants

  float* ws    = (float*)d_ws;
  float* plc   = ws;                // 100*16*441 = 705600
  float* sow   = ws + 705600;       // 512 (500 used)
  float* mask  = ws + 706112;       // 100*5*1764 = 882000
  float* vec_s = ws + 1588112;      // 100*3200 = 320000
  float* vec_r = ws + 1908112;      // 320000
  float* sup   = ws + 2228112;      // 25*3200 = 80000   (total ~9.24 MB)
  float* out   = (float*)d_out;

  hipMemsetAsync(plc, 0, (size_t)706112 * sizeof(float), stream);  // plc + sow
  k1_gate_proj<<<dim3(16, 100), TPB, 0, stream>>>(FL, scw, gng, gnb, mb1w, plc);
  k2_mask<<<dim3(100, 7), TPB, 0, stream>>>(plc, mb1b, bng, bnb, mb2w, mb2b, mask, sow);
  k3_vec<<<dim3(40, 100), TPB, 0, stream>>>(F1, mask, sow, g1d, vec_s, vec_r);
  k4_gemm<<<dim3(400), 128, 0, stream>>>(vec_s, vec_r, linw, linb, b1d, sup, out);
  k5_support<<<dim3(63), TPB, 0, stream>>>(sup, out);
}

// Round 2
// 860.440 us; speedup vs baseline: 1.2266x; 1.2266x over previous
//
#include <hip/hip_runtime.h>
#include <cstddef>

#define TPB 256

__device__ __forceinline__ float sigmoidf_(float x) {
  return 1.0f / (1.0f + __expf(-x));
}

// jax.image.resize bilinear 21->42, half-pixel centers, edge-renormalized
__device__ __forceinline__ void rzmap(int i, int& j0, int& j1, float& w0, float& w1) {
  if (i == 0)            { j0 = 0;  j1 = 0;  w0 = 1.0f;  w1 = 0.0f; }
  else if (i == 41)      { j0 = 20; j1 = 20; w0 = 1.0f;  w1 = 0.0f; }
  else if ((i & 1) == 0) { int k = i >> 1; j0 = k - 1; j1 = k;     w0 = 0.25f; w1 = 0.75f; }
  else                   { int k = i >> 1; j0 = k;     j1 = k + 1; w0 = 0.75f; w1 = 0.25f; }
}

// K1: per (b, group of 32 ch): gates (means -> dwconv -> GN -> sigmoid) and
// gated projection onto mb1_w accumulated atomically into plc[b][16][441].
__global__ __launch_bounds__(256) void k1_gate_proj(
    const float* __restrict__ FL, const float* __restrict__ scw,
    const float* __restrict__ gng, const float* __restrict__ gnb,
    const float* __restrict__ mb1w, float* __restrict__ plc) {
  const int g = blockIdx.x, b = blockIdx.y;
  const int tid = threadIdx.x;
  __shared__ __align__(16) float slab[32 * 441];
  __shared__ float rm[672], cm[672], ch[672], cw[672];
  __shared__ float red[16];

  const float* base = FL + ((size_t)b * 512 + g * 32) * 441;
  const float4* b4 = (const float4*)base;
  float4* sl4 = (float4*)slab;
  for (int i = tid; i < 3528; i += TPB) sl4[i] = b4[i];
  __syncthreads();

  for (int idx = tid; idx < 672; idx += TPB) {
    int c = idx / 21, l = idx - c * 21;
    const float* rowp = slab + c * 441 + l * 21;
    float sr = 0.0f;
    #pragma unroll
    for (int w = 0; w < 21; ++w) sr += rowp[w];
    rm[idx] = sr * (1.0f / 21.0f);
    const float* colp = slab + c * 441 + l;
    float sc = 0.0f;
    #pragma unroll
    for (int h = 0; h < 21; ++h) sc += colp[h * 21];
    cm[idx] = sc * (1.0f / 21.0f);
  }
  __syncthreads();

  for (int idx = tid; idx < 672; idx += TPB) {
    int c = idx / 21, l = idx - c * 21;
    const float* w7 = scw + (g * 32 + c) * 7;
    float ah = 0.0f, aw = 0.0f;
    #pragma unroll
    for (int t = 0; t < 7; ++t) {
      int ll = l + t - 3;
      if (ll >= 0 && ll < 21) {
        float wt = w7[t];
        ah += rm[c * 21 + ll] * wt;
        aw += cm[c * 21 + ll] * wt;
      }
    }
    ch[idx] = ah; cw[idx] = aw;
  }
  __syncthreads();

  float s1 = 0.0f, s2 = 0.0f, s3 = 0.0f, s4v = 0.0f;
  for (int idx = tid; idx < 672; idx += TPB) {
    float x = ch[idx], y = cw[idx];
    s1 += x; s2 += x * x; s3 += y; s4v += y * y;
  }
  #pragma unroll
  for (int off = 32; off; off >>= 1) {
    s1 += __shfl_down(s1, off); s2 += __shfl_down(s2, off);
    s3 += __shfl_down(s3, off); s4v += __shfl_down(s4v, off);
  }
  if ((tid & 63) == 0) {
    int wv = tid >> 6;
    red[wv * 4 + 0] = s1; red[wv * 4 + 1] = s2;
    red[wv * 4 + 2] = s3; red[wv * 4 + 3] = s4v;
  }
  __syncthreads();
  const float S1 = red[0] + red[4] + red[8] + red[12];
  const float S2 = red[1] + red[5] + red[9] + red[13];
  const float S3 = red[2] + red[6] + red[10] + red[14];
  const float S4 = red[3] + red[7] + red[11] + red[15];
  const float invn = 1.0f / 672.0f;
  const float mh = S1 * invn, vh = S2 * invn - mh * mh;
  const float mw = S3 * invn, vw = S4 * invn - mw * mw;
  const float ivh = rsqrtf(vh + 1e-5f), ivw = rsqrtf(vw + 1e-5f);

  for (int idx = tid; idx < 672; idx += TPB) {
    int c = idx / 21;
    float gamma = gng[g * 32 + c], beta = gnb[g * 32 + c];
    ch[idx] = sigmoidf_((ch[idx] - mh) * ivh * gamma + beta);
    cw[idx] = sigmoidf_((cw[idx] - mw) * ivw * gamma + beta);
  }
  __syncthreads();

  float* pp = plc + (size_t)b * 16 * 441;
  for (int p = tid; p < 441; p += TPB) {
    int i = p / 21, j = p - i * 21;
    float acc[16];
    #pragma unroll
    for (int o = 0; o < 16; ++o) acc[o] = 0.0f;
    #pragma unroll 4
    for (int c = 0; c < 32; ++c) {
      float v = slab[c * 441 + p] * ch[c * 21 + i] * cw[c * 21 + j];
      const float* wc = mb1w + g * 32 + c;  // uniform addresses -> s_load
      #pragma unroll
      for (int o = 0; o < 16; ++o) acc[o] += v * wc[o * 512];
    }
    #pragma unroll
    for (int o = 0; o < 16; ++o) atomicAdd(pp + (size_t)o * 441 + p, acc[o]);
  }
}

// K2: bilinear resize of 16-ch plc -> bn -> relu -> mb2 -> sigmoid mask; sow sums
__global__ __launch_bounds__(256) void k2_mask(
    const float* __restrict__ plc, const float* __restrict__ mb1b,
    const float* __restrict__ bng, const float* __restrict__ bnb,
    const float* __restrict__ mb2w, const float* __restrict__ mb2b,
    float* __restrict__ mask, float* __restrict__ sow) {
  const int b = blockIdx.x;
  const int p = blockIdx.y * TPB + threadIdx.x;
  float macc[5] = {0, 0, 0, 0, 0};
  if (p < 1764) {
    int y = p / 42, x = p - y * 42;
    int jy0, jy1, jx0, jx1; float wy0, wy1, wx0, wx1;
    rzmap(y, jy0, jy1, wy0, wy1);
    rzmap(x, jx0, jx1, wx0, wx1);
    const float RSQ = rsqrtf(1.0f + 1e-5f);
    const float* pb = plc + (size_t)b * 16 * 441;
    float h[16];
    #pragma unroll
    for (int o = 0; o < 16; ++o) {
      const float* po = pb + o * 441;
      float hm = wy0 * (wx0 * po[jy0 * 21 + jx0] + wx1 * po[jy0 * 21 + jx1]) +
                 wy1 * (wx0 * po[jy1 * 21 + jx0] + wx1 * po[jy1 * 21 + jx1]);
      float t = (hm + mb1b[o]) * (bng[o] * RSQ) + bnb[o];
      h[o] = t > 0.0f ? t : 0.0f;
    }
    #pragma unroll
    for (int d = 0; d < 5; ++d) {
      float acc = mb2b[d];
      #pragma unroll
      for (int o = 0; o < 16; ++o) acc += mb2w[d * 16 + o] * h[o];
      float mv = sigmoidf_(acc);
      mask[((size_t)b * 5 + d) * 1764 + p] = mv;
      macc[d] = mv;
    }
  }
  #pragma unroll
  for (int off = 32; off; off >>= 1) {
    #pragma unroll
    for (int d = 0; d < 5; ++d) macc[d] += __shfl_down(macc[d], off);
  }
  if ((threadIdx.x & 63) == 0) {
    #pragma unroll
    for (int d = 0; d < 5; ++d) atomicAdd(&sow[b * 5 + d], macc[d]);
  }
}

// K3pre: vec_pad row 100 = bn1d_b (virtual GEMM row -> per-n constant),
// rows 101..127 = 0
__global__ __launch_bounds__(256) void k3pre(
    const float* __restrict__ b1d, float* __restrict__ vp) {
  int i = blockIdx.x * TPB + threadIdx.x;
  if (i >= 28 * 3200) return;
  int r = i / 3200, k = i - r * 3200;
  vp[(size_t)(100 + r) * 3200 + k] = (r == 0) ? b1d[k] : 0.0f;
}

// K3: vec[b,c,d] = (sum_p F1[b,c,p]*mask[b,d,p]) / (sow+1e-5).
// Each wave processes 4 channels simultaneously -> mask LDS reads amortized 4x.
__global__ __launch_bounds__(256) void k3_vec(
    const float* __restrict__ F1, const float* __restrict__ mask,
    const float* __restrict__ sow, const float* __restrict__ g1d,
    float* __restrict__ vec_pad, float* __restrict__ vec_r) {
  const int ct = blockIdx.x, b = blockIdx.y;
  __shared__ float4 mkv[2205];
  const float4* msrc = (const float4*)(mask + (size_t)b * 8820);
  for (int i = threadIdx.x; i < 2205; i += TPB) mkv[i] = msrc[i];
  __syncthreads();
  const int wv = threadIdx.x >> 6, lane = threadIdx.x & 63;
  const int c0 = ct * 16 + wv * 4;
  const float4* f0 = (const float4*)(F1 + ((size_t)b * 640 + c0) * 1764);
  float a[4][5] = {};
  for (int q = lane; q < 441; q += 64) {
    float4 f[4];
    #pragma unroll
    for (int j = 0; j < 4; ++j) f[j] = f0[(size_t)j * 441 + q];
    #pragma unroll
    for (int d = 0; d < 5; ++d) {
      float4 m = mkv[d * 441 + q];
      #pragma unroll
      for (int j = 0; j < 4; ++j)
        a[j][d] += f[j].x * m.x + f[j].y * m.y + f[j].z * m.z + f[j].w * m.w;
    }
  }
  #pragma unroll
  for (int off = 32; off; off >>= 1) {
    #pragma unroll
    for (int j = 0; j < 4; ++j)
      #pragma unroll
      for (int d = 0; d < 5; ++d)
        a[j][d] += __shfl_down(a[j][d], off);
  }
  if (lane == 0) {
    const float RSQ = rsqrtf(1.0f + 1e-5f);
    #pragma unroll
    for (int j = 0; j < 4; ++j) {
      #pragma unroll
      for (int d = 0; d < 5; ++d) {
        float inv = 1.0f / (sow[b * 5 + d] + 1e-5f);
        float val = a[j][d] * inv;
        int k = (c0 + j) * 5 + d;
        vec_r[(size_t)b * 3200 + k] = val;
        vec_pad[(size_t)b * 3200 + k] = val * (g1d[k] * RSQ);
      }
    }
  }
}

// K4: register-tiled fp32 GEMM: dacc[ks] = A(vec_pad 128 rows) @ W^T slice.
// Block tile 64m x 64n, BK=32, thread tile 4x4, K-split by 4 (grid.z).
__global__ __launch_bounds__(256) void k4_gemm(
    const float* __restrict__ A, const float* __restrict__ W,
    float* __restrict__ dacc) {
  const int n0 = blockIdx.x * 64, m0 = blockIdx.y * 64, ks = blockIdx.z;
  const int tid = threadIdx.x, tx = tid & 15, ty = tid >> 4;
  __shared__ float4 As[512], Ws[512];   // [kq 0..7][row 0..63]
  const int lr = tid >> 3, lq = tid & 7;  // staging: 32 rows/pass, 8 f4 per row
  const float4* Ag = (const float4*)(A + (size_t)(m0 + lr) * 3200) + ks * 200 + lq;
  const float4* Wg = (const float4*)(W + (size_t)(n0 + lr) * 3200) + ks * 200 + lq;
  const float4* Ag2 = Ag + 32 * 800;
  const float4* Wg2 = Wg + 32 * 800;
  float acc[4][4] = {};
  for (int kk = 0; kk < 25; ++kk) {
    __syncthreads();
    As[lq * 64 + lr]      = Ag[kk * 8];
    As[lq * 64 + lr + 32] = Ag2[kk * 8];
    Ws[lq * 64 + lr]      = Wg[kk * 8];
    Ws[lq * 64 + lr + 32] = Wg2[kk * 8];
    __syncthreads();
    #pragma unroll
    for (int kq = 0; kq < 8; ++kq) {
      float4 av[4], wv4[4];
      #pragma unroll
      for (int r = 0; r < 4; ++r) av[r] = As[kq * 64 + ty + 16 * r];
      #pragma unroll
      for (int s = 0; s < 4; ++s) wv4[s] = Ws[kq * 64 + tx + 16 * s];
      #pragma unroll
      for (int r = 0; r < 4; ++r)
        #pragma unroll
        for (int s = 0; s < 4; ++s)
          acc[r][s] += av[r].x * wv4[s].x + av[r].y * wv4[s].y +
                       av[r].z * wv4[s].z + av[r].w * wv4[s].w;
    }
  }
  float* dp = dacc + (size_t)ks * 128 * 3200;
  #pragma unroll
  for (int r = 0; r < 4; ++r) {
    int m = m0 + ty + 16 * r;
    #pragma unroll
    for (int s = 0; s < 4; ++s)
      dp[(size_t)m * 3200 + n0 + tx + 16 * s] = acc[r][s];
  }
}

// K4b: sum 4 K-slices, add c0 (virtual row 100) + lin_b, elu, combine with vec
__global__ __launch_bounds__(256) void k4b_epi(
    const float* __restrict__ dacc, const float* __restrict__ linb,
    const float* __restrict__ vec_r, float* __restrict__ sup,
    float* __restrict__ outq) {
  int i = blockIdx.x * TPB + threadIdx.x;
  if (i >= 320000) return;
  int m = i / 3200, n = i - m * 3200;
  const size_t S = (size_t)128 * 3200;
  size_t o = (size_t)m * 3200 + n;
  size_t oc = (size_t)100 * 3200 + n;
  float d  = dacc[o] + dacc[S + o] + dacc[2 * S + o] + dacc[3 * S + o];
  float c0 = dacc[oc] + dacc[S + oc] + dacc[2 * S + oc] + dacc[3 * S + oc];
  float dv = d + c0 + linb[n];
  float z = dv > 0.0f ? dv : expm1f(dv);
  float out = 0.5f * z + 0.5f * vec_r[i];
  if (m < 25) sup[(size_t)m * 3200 + n] = out;
  else outq[(size_t)(m - 20) * 3200 + n] = out;  // query rows 5..79 of d_out
}

// K5: support = mean over 5 shots of first 25 rows
__global__ __launch_bounds__(256) void k5_support(
    const float* __restrict__ sup, float* __restrict__ outp) {
  int idx = blockIdx.x * TPB + threadIdx.x;
  if (idx >= 16000) return;
  int w = idx / 3200, n = idx - w * 3200;
  float s = 0.0f;
  #pragma unroll
  for (int t = 0; t < 5; ++t) s += sup[(size_t)(w * 5 + t) * 3200 + n];
  outp[idx] = s * 0.2f;
}

extern "C" void kernel_launch(void* const* d_in, const int* in_sizes, int n_in,
                              void* d_out, int out_size, void* d_ws, size_t ws_size,
                              hipStream_t stream) {
  const float* F1   = (const float*)d_in[0];
  const float* FL   = (const float*)d_in[1];
  const float* scw  = (const float*)d_in[2];
  const float* gng  = (const float*)d_in[3];
  const float* gnb  = (const float*)d_in[4];
  const float* mb1w = (const float*)d_in[5];
  const float* mb1b = (const float*)d_in[6];
  const float* bng  = (const float*)d_in[7];
  const float* bnb  = (const float*)d_in[8];
  const float* mb2w = (const float*)d_in[9];
  const float* mb2b = (const float*)d_in[10];
  const float* g1d  = (const float*)d_in[11];
  const float* b1d  = (const float*)d_in[12];
  const float* linw = (const float*)d_in[13];
  const float* linb = (const float*)d_in[14];

  float* ws      = (float*)d_ws;
  float* plc     = ws;                 // 705600
  float* sow     = ws + 705600;        // 512
  float* mask    = ws + 706112;        // 882000
  float* vec_pad = ws + 1588112;       // 128*3200 = 409600
  float* vec_r   = ws + 1997712;       // 320000
  float* dacc    = ws + 2317712;       // 4*128*3200 = 1638400
  float* sup     = ws + 3956112;       // 80000  (total ~16.1 MB)
  float* out     = (float*)d_out;

  hipMemsetAsync(plc, 0, (size_t)706112 * sizeof(float), stream);  // plc + sow
  k3pre<<<dim3(350), TPB, 0, stream>>>(b1d, vec_pad);
  k1_gate_proj<<<dim3(16, 100), TPB, 0, stream>>>(FL, scw, gng, gnb, mb1w, plc);
  k2_mask<<<dim3(100, 7), TPB, 0, stream>>>(plc, mb1b, bng, bnb, mb2w, mb2b, mask, sow);
  k3_vec<<<dim3(40, 100), TPB, 0, stream>>>(F1, mask, sow, g1d, vec_pad, vec_r);
  k4_gemm<<<dim3(50, 2, 4), TPB, 0, stream>>>(vec_pad, linw, dacc);
  k4b_epi<<<dim3(1250), TPB, 0, stream>>>(dacc, linb, vec_r, sup, out);
  k5_support<<<dim3(63), TPB, 0, stream>>>(sup, out);
}